// Round 5
// baseline (302.848 us; speedup 1.0000x reference)
//
#include <hip/hip_runtime.h>
#include <cstdint>

// ---------------------------------------------------------------------------
// AttentionAIC: dual-stream QKV proj + per-head RMSNorm + joint SDPA + out-proj
// B=1, S=2048, S_enc=256, D=1536, H=24, HD=64, T=2304.
// Context output discarded -> skip add_q_proj, encoder q-rows, to_add_out.
// R11: GEMM back to 128x128 (R10's 64x128 regressed: 1.5x staged-bytes/FLOP).
// Two structural fixes on the R9 GEMM:
//  (a) double-buffered LDS (32KB), ONE barrier/iter: stage(it+1) issued
//      before compute(it) -> global->LDS latency hidden under MFMA+reads
//      (the flash kernel's proven pattern; old loop was stage->bar->comp->bar
//      with latency fully exposed).
//  (b) T2 bank-conflict swizzle: fragment reads walked 64B-stride rows ->
//      8-way conflict (3.8M cyc). Store chunk c of row r at c^((r>>1)&3)
//      via pre-swizzled gload_lds SOURCE; read with same XOR (lane-constant
//      quad^((l16>>1)&3)). Residual 2-way = free.
// Worklist + XCD-chunked swizzle unchanged from R9. flash v7 unchanged.
// ---------------------------------------------------------------------------

typedef __attribute__((ext_vector_type(8))) short s16x8;   // 8 x bf16
typedef __attribute__((ext_vector_type(4))) float f32x4;

#define LOG2E 1.4426950408889634f

__device__ __forceinline__ short f2bf(float f) {          // RNE (epilogues)
  union { float f; uint32_t u; } v; v.f = f;
  uint32_t r = v.u + 0x7FFFu + ((v.u >> 16) & 1u);
  return (short)(r >> 16);
}

__device__ __forceinline__ uint32_t cvt_pk_bf16(float lo, float hi) {
  uint32_t r;
  asm("v_cvt_pk_bf16_f32 %0, %1, %2" : "=v"(r) : "v"(lo), "v"(hi));
  return r;
}

typedef uint32_t __attribute__((address_space(1)))* gas_u32;
typedef uint32_t __attribute__((address_space(3)))* las_u32;

// async global->LDS, 16B per lane; dest must be wave-uniform base + lane*16
__device__ __forceinline__ void gload_lds16(const short* g, short* l) {
  __builtin_amdgcn_global_load_lds((gas_u32)(g), (las_u32)(l), 16, 0, 0);
}

// ---------------------------------------------------------------------------
// fp32 -> bf16 conversion (8 segments) + mask*LOG2E f32 table, one launch
// ---------------------------------------------------------------------------
struct CvtSeg { const float* src; short* dst; int n4; };
struct CvtArgs { CvtSeg s[8]; const float* msrc; float* mdst; int mn4; };

__global__ __launch_bounds__(256) void cvt_bf16_kernel(CvtArgs a) {
  const int stride = gridDim.x * blockDim.x;
  const int tid = blockIdx.x * blockDim.x + threadIdx.x;
  for (int i = 0; i < 8; ++i) {
    const float4* src = (const float4*)a.s[i].src;
    short* dst = a.s[i].dst;
    const int n4 = a.s[i].n4;
    for (int j = tid; j < n4; j += stride) {
      float4 v = src[j];
      short4 o;
      o.x = f2bf(v.x); o.y = f2bf(v.y); o.z = f2bf(v.z); o.w = f2bf(v.w);
      *(short4*)(dst + (size_t)j * 4) = o;
    }
  }
  const float4* ms = (const float4*)a.msrc;
  float4* md = (float4*)a.mdst;
  for (int j = tid; j < a.mn4; j += stride) {
    float4 m = ms[j];
    float4 o = {m.x * LOG2E, m.y * LOG2E, m.z * LOG2E, m.w * LOG2E};
    md[j] = o;
  }
}

// ---------------------------------------------------------------------------
// GEMM: C[M,1536] = A[M,1536] @ W[1536,1536]^T (+bias), fused epilogues.
// 128x128 tile, BK=32, 4 waves (2x2), wave = 64x64 via 4x4 MFMA.
// Double-buffered LDS (2x8KB A + 2x8KB B = 32KB), one barrier per K-iter.
// LDS chunk-swizzle: slot (row r, chunk c) holds global chunk c^((r>>1)&3).
// 1D worklist, y-fastest within (z, x-panel), XCD-chunked bijective swizzle:
//   w < 576: z=w/192, x=(w%192)/16, y=w%16   (hidden: Q,K,V - 16 M-tiles)
//   else   : r=w-576, z=3+r/24, x=(r%24)/2, y=r&1 (encoder: K,V - 2 M-tiles)
// out-proj: 192 tiles -> same decode (w<192 -> z=0).
// ---------------------------------------------------------------------------
enum { MODE_Q = 0, MODE_K = 1, MODE_V = 2, MODE_OUT = 3 };

struct GemmCfg {
  const short* A;      // [M,1536] bf16
  const short* W;      // [1536,1536] bf16, row-major [N][K]
  const float* bias;   // [1536] fp32
  const float* normw;  // [64] fp32 (Q/K modes)
  void* dst;
  int toff;            // t offset for K/V (0 hidden, 2048 encoder)
  int mode;
  int pad;
};
struct GemmArgs { GemmCfg c[5]; };

__global__ __launch_bounds__(256) void proj_gemm_kernel(GemmArgs args, int chunk) {
  // bijective XCD swizzle: grid size is a multiple of 8, chunk = grid/8
  const int w = (blockIdx.x & 7) * chunk + (blockIdx.x >> 3);
  int z, tx, ty;
  if (w < 576) { z = w / 192; const int r = w % 192; tx = r >> 4; ty = r & 15; }
  else { int r = w - 576; z = 3 + r / 24; r %= 24; tx = r >> 1; ty = r & 1; }
  const GemmCfg cfg = args.c[z];
  constexpr int K = 1536;
  __shared__ short As[8192];  // 2 x [128][32]
  __shared__ short Bs[8192];  // 2 x [128][32]
  const int t = threadIdx.x;
  const int lane = t & 63;
  const int wave = t >> 6;
  const int l16 = lane & 15;
  const int quad = lane >> 4;
  const int wm = wave >> 1;
  const int wn = wave & 1;

  const short* __restrict__ Ag = cfg.A + (size_t)(ty * 128) * K;
  const short* __restrict__ Wg = cfg.W + (size_t)(tx * 128) * K;
  const int srow = t >> 2;                              // 0..63
  const int ssw = ((t & 3) ^ ((srow >> 1) & 3)) << 3;   // swizzled src chunk
  // (rows srow and srow+64 share the same swizzle: 64 == 0 mod 4 after >>1)

  const f32x4 z4 = {0.f, 0.f, 0.f, 0.f};
  f32x4 acc[4][4];
#pragma unroll
  for (int i = 0; i < 4; ++i) {
#pragma unroll
    for (int j = 0; j < 4; ++j) acc[i][j] = z4;
  }

  auto stage = [&](int it, int buf) {
    const int k0 = it * 32;
    short* a = As + buf * 4096;
    short* b = Bs + buf * 4096;
    gload_lds16(Ag + (size_t)srow * K + k0 + ssw, a + t * 8);
    gload_lds16(Ag + (size_t)(srow + 64) * K + k0 + ssw, a + 2048 + t * 8);
    gload_lds16(Wg + (size_t)srow * K + k0 + ssw, b + t * 8);
    gload_lds16(Wg + (size_t)(srow + 64) * K + k0 + ssw, b + 2048 + t * 8);
  };

  stage(0, 0);
  __syncthreads();   // implicit vmcnt(0): tile 0 landed

  const int rsw = (quad ^ ((l16 >> 1) & 3)) << 3;  // read-side XOR (lane-const)

#pragma unroll 2
  for (int it = 0; it < 48; ++it) {
    const int buf = it & 1;
    if (it < 47) stage(it + 1, buf ^ 1);
    const short* a = As + buf * 4096;
    const short* b = Bs + buf * 4096;
    s16x8 af[4], bfr[4];
#pragma unroll
    for (int i = 0; i < 4; ++i)
      af[i] = *(const s16x8*)(a + (wm * 64 + i * 16 + l16) * 32 + rsw);
#pragma unroll
    for (int i = 0; i < 4; ++i)
      bfr[i] = *(const s16x8*)(b + (wn * 64 + i * 16 + l16) * 32 + rsw);
#pragma unroll
    for (int mi = 0; mi < 4; ++mi) {
#pragma unroll
      for (int ni = 0; ni < 4; ++ni)
        acc[mi][ni] = __builtin_amdgcn_mfma_f32_16x16x32_bf16(af[mi], bfr[ni], acc[mi][ni], 0, 0, 0);
    }
    __syncthreads();  // readers done with buf; next-tile staging (buf^1) drained
  }

  // epilogue: C/D layout col=lane&15, row=quad*4+reg
  const int nbase = tx * 128 + wn * 64;   // 64-aligned -> one head/wave
  const int mbase = ty * 128 + wm * 64;
  const int mode = cfg.mode;
  const int h = nbase >> 6;

  float biasv[4], nwv[4];
#pragma unroll
  for (int ni = 0; ni < 4; ++ni) {
    int col = nbase + ni * 16 + l16;
    biasv[ni] = cfg.bias[col];
    nwv[ni] = (mode == MODE_Q || mode == MODE_K) ? cfg.normw[col & 63] : 0.f;
  }

#pragma unroll
  for (int mi = 0; mi < 4; ++mi) {
    float vv[4][4];
#pragma unroll
    for (int ni = 0; ni < 4; ++ni) {
#pragma unroll
      for (int r = 0; r < 4; ++r) vv[ni][r] = acc[mi][ni][r] + biasv[ni];
    }
    if (mode == MODE_Q || mode == MODE_K) {
      float ss[4];
#pragma unroll
      for (int r = 0; r < 4; ++r)
        ss[r] = vv[0][r] * vv[0][r] + vv[1][r] * vv[1][r] +
                vv[2][r] * vv[2][r] + vv[3][r] * vv[3][r];
#pragma unroll
      for (int r = 0; r < 4; ++r) {
        ss[r] += __shfl_xor(ss[r], 1);
        ss[r] += __shfl_xor(ss[r], 2);
        ss[r] += __shfl_xor(ss[r], 4);
        ss[r] += __shfl_xor(ss[r], 8);
        float rs = rsqrtf(ss[r] * (1.0f / 64.0f) + 1e-6f);
#pragma unroll
        for (int ni = 0; ni < 4; ++ni) vv[ni][r] *= rs * nwv[ni];
      }
    }
    const int row0 = mbase + mi * 16 + quad * 4;  // + r
    if (mode == MODE_Q) {
      short* Qd = (short*)cfg.dst;  // [24][2048][64]
#pragma unroll
      for (int ni = 0; ni < 4; ++ni) {
        int d = ni * 16 + l16;
#pragma unroll
        for (int r = 0; r < 4; ++r)
          Qd[((size_t)h * 2048 + row0 + r) * 64 + d] = f2bf(vv[ni][r]);
      }
    } else if (mode == MODE_K) {
      short* Kd = (short*)cfg.dst;  // [24][2304][64]
#pragma unroll
      for (int ni = 0; ni < 4; ++ni) {
        int d = ni * 16 + l16;
#pragma unroll
        for (int r = 0; r < 4; ++r)
          Kd[((size_t)h * 2304 + cfg.toff + row0 + r) * 64 + d] = f2bf(vv[ni][r]);
      }
    } else if (mode == MODE_V) {
      short* Vd = (short*)cfg.dst;  // V^T: [24][64][2304]
#pragma unroll
      for (int ni = 0; ni < 4; ++ni) {
        int d = ni * 16 + l16;
        short4 o4;
        o4.x = f2bf(vv[ni][0]); o4.y = f2bf(vv[ni][1]);
        o4.z = f2bf(vv[ni][2]); o4.w = f2bf(vv[ni][3]);
        *(short4*)(Vd + ((size_t)h * 64 + d) * 2304 + cfg.toff + row0) = o4;
      }
    } else {  // MODE_OUT: fp32 row-major [2048][1536]
      float* Od = (float*)cfg.dst;
#pragma unroll
      for (int ni = 0; ni < 4; ++ni) {
        int col = nbase + ni * 16 + l16;
#pragma unroll
        for (int r = 0; r < 4; ++r)
          Od[(size_t)(row0 + r) * 1536 + col] = vv[ni][r];
      }
    }
  }
}

// ---------------------------------------------------------------------------
// Flash attention v7: block = (64 q-rows, head). Wave w: qw=w&1 owns 32
// q-rows (two 16-row groups), ks=w>>1 owns a 1152-k stream (36 x 32-t tiles).
// QK^T SWAPPED (mfma(K,Q)) with sigma-permuted K rows so the lane's 8 post-
// exp2 P values (cvt_pk-packed) form the PV 16x16x32 A-fragment in registers.
// l = P @ ones via MFMA (C-layout row=quad*4+rr matches o). mask*LOG2E
// pre-tabulated. Staging offsets hoisted. LDS 32KB, grid 768.
// ---------------------------------------------------------------------------
__global__ __launch_bounds__(256) void flash_kernel(
    const short* __restrict__ Q, const short* __restrict__ Kc,
    const short* __restrict__ VT, const float* __restrict__ mlt,
    short* __restrict__ AO) {
  const int b = blockIdx.x;
  const int h = (b & 7) * 3 + ((b >> 3) % 3);
  const int q0 = ((b >> 3) / 3) * 64;
  const int lane = threadIdx.x & 63;
  const int wave = threadIdx.x >> 6;
  const int qw = wave & 1;   // which 32-row q half
  const int ks = wave >> 1;  // k stream
  const int l16 = lane & 15;
  const int quad = lane >> 4;

  // shorts: Kt (ks*2+buf)*2048 @0 ; Vt @8192. 32 KB total.
  __shared__ __align__(16) short smem[16384];

  const short* Kh = Kc + (size_t)h * 2304 * 64;
  const short* Vh = VT + (size_t)h * 64 * 2304;

  // Q fragments for this wave's two 16-row groups (B-operand in swapped QK^T)
  s16x8 aq0[2], aq1[2];
#pragma unroll
  for (int g = 0; g < 2; ++g) {
    const short* Qrow =
        Q + ((size_t)h * 2048 + q0 + qw * 32 + g * 16 + l16) * 64;
    aq0[g] = *(const s16x8*)(Qrow + quad * 8);
    aq1[g] = *(const s16x8*)(Qrow + quad * 8 + 32);
  }

  s16x8 ones;
#pragma unroll
  for (int i = 0; i < 8; ++i) ones[i] = (short)0x3F80;  // bf16 1.0

  const f32x4 z4 = {0.f, 0.f, 0.f, 0.f};
  f32x4 o[2][4];
#pragma unroll
  for (int g = 0; g < 2; ++g)
#pragma unroll
    for (int mi = 0; mi < 4; ++mi) o[g][mi] = z4;
  f32x4 lacc[2] = {z4, z4};
  const float SC = 0.125f * LOG2E;
  const int kbase = ks * 1152;

  // hoisted per-lane staging source offsets (c=0; c=1 = +256 / +32*2304):
  // K: trow=gi>>3 in [0,16), srow=((trow&12)<<1)|(trow&3), chunk=cp^(trow&7)
  // V: d=gi>>2 in [0,32), chunk=cpv^((d>>1)&3)
  const int gi0 = qw * 64 + lane;
  const int trow0 = gi0 >> 3, cp0 = gi0 & 7;
  const int srow0 = ((trow0 & 12) << 1) | (trow0 & 3);
  const int d0 = gi0 >> 2, cpv0 = gi0 & 3;
  const short* kS = Kh + (size_t)kbase * 64 + srow0 * 64 + ((cp0 ^ (trow0 & 7)) << 3);
  const short* vS = Vh + (size_t)d0 * 2304 + kbase + ((cpv0 ^ ((d0 >> 1) & 3)) << 3);
  const int ldst = qw * 512 + lane * 8;   // wave-uniform base + lane*16B

  auto stage = [&](int it, int buf) {
    short* kt = smem + (ks * 2 + buf) * 2048;
    short* vt = smem + 8192 + (ks * 2 + buf) * 2048;
    const short* ksrc = kS + it * 2048;
    const short* vsrc = vS + it * 32;
    gload_lds16(ksrc,             kt + ldst);
    gload_lds16(ksrc + 256,       kt + 1024 + ldst);
    gload_lds16(vsrc,             vt + ldst);
    gload_lds16(vsrc + 32 * 2304, vt + 1024 + ldst);
  };

  stage(0, 0);
  __syncthreads();

#pragma unroll 2
  for (int it = 0; it < 36; ++it) {
    const int buf = it & 1;
    if (it < 35) stage(it + 1, buf ^ 1);
    const short* kt = smem + (ks * 2 + buf) * 2048;
    const short* vt = smem + 8192 + (ks * 2 + buf) * 2048;
    const int kb = kbase + it * 32;

    // K fragments (A-operand of swapped QK^T): rows = permuted keys
    s16x8 bk[2][2];
#pragma unroll
    for (int ni = 0; ni < 2; ++ni) {
      const int tt = ni * 16 + l16;
      const short* kr = kt + tt * 64;
      bk[ni][0] = *(const s16x8*)(kr + ((quad ^ (tt & 7)) << 3));
      bk[ni][1] = *(const s16x8*)(kr + (((quad + 4) ^ (tt & 7)) << 3));
    }
    // V fragments (B-operand of PV, k=quad*8+j): shared by both q-groups
    s16x8 bv[4];
#pragma unroll
    for (int mi = 0; mi < 4; ++mi) {
      const int d = mi * 16 + l16;
      bv[mi] = *(const s16x8*)(vt + d * 32 + ((quad ^ ((d >> 1) & 3)) << 3));
    }
    // mask*LOG2E for this lane's 8 keys: k = kb + quad*8 + {0..7}
    float4 mv0 = *(const float4*)(mlt + kb + quad * 8);
    float4 mv1 = *(const float4*)(mlt + kb + quad * 8 + 4);
    const float m8[8] = {mv0.x, mv0.y, mv0.z, mv0.w, mv1.x, mv1.y, mv1.z, mv1.w};

#pragma unroll
    for (int g = 0; g < 2; ++g) {
      union { uint32_t w[4]; s16x8 v; } pu;
#pragma unroll
      for (int ni = 0; ni < 2; ++ni) {
        // S^T tile: lane holds q=l16, k(actual) = quad*8 + ni*4 + rr
        f32x4 s = __builtin_amdgcn_mfma_f32_16x16x32_bf16(bk[ni][0], aq0[g], z4, 0, 0, 0);
        s = __builtin_amdgcn_mfma_f32_16x16x32_bf16(bk[ni][1], aq1[g], s, 0, 0, 0);
        float p[4];
#pragma unroll
        for (int rr = 0; rr < 4; ++rr)
          p[rr] = __builtin_amdgcn_exp2f(fmaf(s[rr], SC, m8[ni * 4 + rr]));
        pu.w[ni * 2 + 0] = cvt_pk_bf16(p[0], p[1]);
        pu.w[ni * 2 + 1] = cvt_pk_bf16(p[2], p[3]);
      }
      // pu.v IS the PV A-fragment: element j = P[q=l16][k=quad*8+j]
      lacc[g] = __builtin_amdgcn_mfma_f32_16x16x32_bf16(pu.v, ones, lacc[g], 0, 0, 0);
#pragma unroll
      for (int mi = 0; mi < 4; ++mi)
        o[g][mi] = __builtin_amdgcn_mfma_f32_16x16x32_bf16(pu.v, bv[mi], o[g][mi], 0, 0, 0);
    }
    __syncthreads();   // next tile's staging landed during compute
  }

  // cross-stream combine: ks=1 dumps (o, l) to LDS, ks=0 sums and writes.
  // Both o and lacc have C-layout row=quad*4+rr, so normalize is direct.
  f32x4* R = (f32x4*)smem;               // [128][10] f32x4 = 20 KB
  if (ks == 1) {
    f32x4* Rw = R + (qw * 64 + lane) * 10;
#pragma unroll
    for (int g = 0; g < 2; ++g) {
#pragma unroll
      for (int mi = 0; mi < 4; ++mi) Rw[g * 5 + mi] = o[g][mi];
      Rw[g * 5 + 4] = lacc[g];
    }
  }
  __syncthreads();
  if (ks == 0) {
    const f32x4* Rw = R + (qw * 64 + lane) * 10;
#pragma unroll
    for (int g = 0; g < 2; ++g) {
#pragma unroll
      for (int mi = 0; mi < 4; ++mi) o[g][mi] += Rw[g * 5 + mi];
      f32x4 lt = lacc[g] + Rw[g * 5 + 4];
#pragma unroll
      for (int rr = 0; rr < 4; ++rr) {
        float inv = 1.0f / lt[rr];
        int tq = q0 + qw * 32 + g * 16 + quad * 4 + rr;
#pragma unroll
        for (int mi = 0; mi < 4; ++mi)
          AO[(size_t)tq * 1536 + h * 64 + mi * 16 + l16] = f2bf(o[g][mi][rr] * inv);
      }
    }
  }
}

// ---------------------------------------------------------------------------
extern "C" void kernel_launch(void* const* d_in, const int* in_sizes, int n_in,
                              void* d_out, int out_size, void* d_ws, size_t ws_size,
                              hipStream_t stream) {
  (void)in_sizes; (void)n_in; (void)out_size; (void)ws_size;
  const float* hidden = (const float*)d_in[0];
  const float* enc    = (const float*)d_in[1];
  const float* amask  = (const float*)d_in[2];
  const float* wq  = (const float*)d_in[3];  const float* bq  = (const float*)d_in[4];
  const float* wk  = (const float*)d_in[5];  const float* bk  = (const float*)d_in[6];
  const float* wv  = (const float*)d_in[7];  const float* bv  = (const float*)d_in[8];
  const float* nqw = (const float*)d_in[9];  const float* nkw = (const float*)d_in[10];
  // d_in[11],[12],[17]: add_q_proj + norm_added_q -> dead (context q unused)
  const float* wak = (const float*)d_in[13]; const float* bak = (const float*)d_in[14];
  const float* wav = (const float*)d_in[15]; const float* bav = (const float*)d_in[16];
  const float* nakw = (const float*)d_in[18];
  const float* wo  = (const float*)d_in[19]; const float* bo  = (const float*)d_in[20];
  // d_in[21],[22]: to_add_out -> dead
  float* out = (float*)d_out;

  char* p = (char*)d_ws;
  auto carve = [&](size_t bytes) { char* r = p; p += (bytes + 255) & ~(size_t)255; return r; };
  short* Xb   = (short*)carve((size_t)2048 * 1536 * 2);
  short* Eb   = (short*)carve((size_t)256 * 1536 * 2);
  short* Wqb  = (short*)carve((size_t)1536 * 1536 * 2);
  short* Wkb  = (short*)carve((size_t)1536 * 1536 * 2);
  short* Wvb  = (short*)carve((size_t)1536 * 1536 * 2);
  short* Wakb = (short*)carve((size_t)1536 * 1536 * 2);
  short* Wavb = (short*)carve((size_t)1536 * 1536 * 2);
  short* Wob  = (short*)carve((size_t)1536 * 1536 * 2);
  short* Qb   = (short*)carve((size_t)24 * 2048 * 64 * 2);
  short* Kb   = (short*)carve((size_t)24 * 2304 * 64 * 2);
  short* VTb  = (short*)carve((size_t)24 * 64 * 2304 * 2);
  short* AOb  = (short*)carve((size_t)2048 * 1536 * 2);
  float* MLb  = (float*)carve((size_t)2304 * 4);

  CvtArgs ca;
  ca.s[0] = {hidden, Xb, 2048 * 1536 / 4};
  ca.s[1] = {enc,    Eb, 256 * 1536 / 4};
  ca.s[2] = {wq,  Wqb,  1536 * 1536 / 4};
  ca.s[3] = {wk,  Wkb,  1536 * 1536 / 4};
  ca.s[4] = {wv,  Wvb,  1536 * 1536 / 4};
  ca.s[5] = {wak, Wakb, 1536 * 1536 / 4};
  ca.s[6] = {wav, Wavb, 1536 * 1536 / 4};
  ca.s[7] = {wo,  Wob,  1536 * 1536 / 4};
  ca.msrc = amask; ca.mdst = MLb; ca.mn4 = 2304 / 4;
  cvt_bf16_kernel<<<dim3(1024), dim3(256), 0, stream>>>(ca);

  GemmArgs g1;  // all five projections, 1D worklist of 624 tiles
  g1.c[0] = {Xb, Wqb,  bq,  nqw,     (void*)Qb,  0,    MODE_Q, 0};
  g1.c[1] = {Xb, Wkb,  bk,  nkw,     (void*)Kb,  0,    MODE_K, 0};
  g1.c[2] = {Xb, Wvb,  bv,  nullptr, (void*)VTb, 0,    MODE_V, 0};
  g1.c[3] = {Eb, Wakb, bak, nakw,    (void*)Kb,  2048, MODE_K, 0};
  g1.c[4] = {Eb, Wavb, bav, nullptr, (void*)VTb, 2048, MODE_V, 0};
  proj_gemm_kernel<<<dim3(624), dim3(256), 0, stream>>>(g1, 78);

  flash_kernel<<<dim3(768), dim3(256), 0, stream>>>(Qb, Kb, VTb, MLb, AOb);

  GemmArgs g3;  // out projection -> fp32 d_out (192 tiles, w<192 -> z=0)
  g3.c[0] = {AOb, Wob, bo, nullptr, (void*)out, 0, MODE_OUT, 0};
  proj_gemm_kernel<<<dim3(192), dim3(256), 0, stream>>>(g3, 24);
}

// Round 6
// 273.471 us; speedup vs baseline: 1.1074x; 1.1074x over previous
//
#include <hip/hip_runtime.h>
#include <cstdint>

// ---------------------------------------------------------------------------
// AttentionAIC: dual-stream QKV proj + per-head RMSNorm + joint SDPA + out-proj
// B=1, S=2048, S_enc=256, D=1536, H=24, HD=64, T=2304.
// Context output discarded -> skip add_q_proj, encoder q-rows, to_add_out.
// R12: GEMM = exact R9 structure (128x128, BK=32, TWO barriers, 16KB LDS --
// R11's one-barrier dbuf regressed 53->77us and is reverted) + the ONE
// component R11 proved safe: both-sides chunk swizzle. Staging stores global
// chunk c^((r>>1)&3) in slot (r,c) via pre-swizzled gload_lds SOURCE; reads
// XOR the same (lane-const quad^((l16>>1)&3)). R11 measured: conflicts
// 3.83M -> 0, absmax unchanged. Theory: R9 is LDS-pipe-saturated at 2.44
// blocks/CU (conflicted demand ~3120 cyc/iter > 2660 wall; free ~1250).
// Worklist + XCD chunking unchanged from R9. flash v7 unchanged from R8.
// ---------------------------------------------------------------------------

typedef __attribute__((ext_vector_type(8))) short s16x8;   // 8 x bf16
typedef __attribute__((ext_vector_type(4))) float f32x4;

#define LOG2E 1.4426950408889634f

__device__ __forceinline__ short f2bf(float f) {          // RNE (epilogues)
  union { float f; uint32_t u; } v; v.f = f;
  uint32_t r = v.u + 0x7FFFu + ((v.u >> 16) & 1u);
  return (short)(r >> 16);
}

__device__ __forceinline__ uint32_t cvt_pk_bf16(float lo, float hi) {
  uint32_t r;
  asm("v_cvt_pk_bf16_f32 %0, %1, %2" : "=v"(r) : "v"(lo), "v"(hi));
  return r;
}

typedef uint32_t __attribute__((address_space(1)))* gas_u32;
typedef uint32_t __attribute__((address_space(3)))* las_u32;

// async global->LDS, 16B per lane; dest must be wave-uniform base + lane*16
__device__ __forceinline__ void gload_lds16(const short* g, short* l) {
  __builtin_amdgcn_global_load_lds((gas_u32)(g), (las_u32)(l), 16, 0, 0);
}

// ---------------------------------------------------------------------------
// fp32 -> bf16 conversion (8 segments) + mask*LOG2E f32 table, one launch
// ---------------------------------------------------------------------------
struct CvtSeg { const float* src; short* dst; int n4; };
struct CvtArgs { CvtSeg s[8]; const float* msrc; float* mdst; int mn4; };

__global__ __launch_bounds__(256) void cvt_bf16_kernel(CvtArgs a) {
  const int stride = gridDim.x * blockDim.x;
  const int tid = blockIdx.x * blockDim.x + threadIdx.x;
  for (int i = 0; i < 8; ++i) {
    const float4* src = (const float4*)a.s[i].src;
    short* dst = a.s[i].dst;
    const int n4 = a.s[i].n4;
    for (int j = tid; j < n4; j += stride) {
      float4 v = src[j];
      short4 o;
      o.x = f2bf(v.x); o.y = f2bf(v.y); o.z = f2bf(v.z); o.w = f2bf(v.w);
      *(short4*)(dst + (size_t)j * 4) = o;
    }
  }
  const float4* ms = (const float4*)a.msrc;
  float4* md = (float4*)a.mdst;
  for (int j = tid; j < a.mn4; j += stride) {
    float4 m = ms[j];
    float4 o = {m.x * LOG2E, m.y * LOG2E, m.z * LOG2E, m.w * LOG2E};
    md[j] = o;
  }
}

// ---------------------------------------------------------------------------
// GEMM: C[M,1536] = A[M,1536] @ W[1536,1536]^T (+bias), fused epilogues.
// 128x128 tile, BK=32, 4 waves (2x2), wave = 64x64 via 4x4 MFMA. 16KB LDS,
// two barriers per K-iter (R9-proven). Chunk swizzle: slot (row r, chunk c)
// holds global chunk c^((r>>1)&3); reads XOR with quad^((l16>>1)&3).
// 1D worklist, y-fastest within (z, x-panel), XCD-chunked bijective swizzle:
//   w < 576: z=w/192, x=(w%192)/16, y=w%16   (hidden: Q,K,V - 16 M-tiles)
//   else   : r=w-576, z=3+r/24, x=(r%24)/2, y=r&1 (encoder: K,V - 2 M-tiles)
// out-proj: 192 tiles -> same decode (w<192 -> z=0).
// ---------------------------------------------------------------------------
enum { MODE_Q = 0, MODE_K = 1, MODE_V = 2, MODE_OUT = 3 };

struct GemmCfg {
  const short* A;      // [M,1536] bf16
  const short* W;      // [1536,1536] bf16, row-major [N][K]
  const float* bias;   // [1536] fp32
  const float* normw;  // [64] fp32 (Q/K modes)
  void* dst;
  int toff;            // t offset for K/V (0 hidden, 2048 encoder)
  int mode;
  int pad;
};
struct GemmArgs { GemmCfg c[5]; };

__global__ __launch_bounds__(256) void proj_gemm_kernel(GemmArgs args, int chunk) {
  // bijective XCD swizzle: grid size is a multiple of 8, chunk = grid/8
  const int w = (blockIdx.x & 7) * chunk + (blockIdx.x >> 3);
  int z, tx, ty;
  if (w < 576) { z = w / 192; const int r = w % 192; tx = r >> 4; ty = r & 15; }
  else { int r = w - 576; z = 3 + r / 24; r %= 24; tx = r >> 1; ty = r & 1; }
  const GemmCfg cfg = args.c[z];
  constexpr int K = 1536;
  __shared__ short As[4096];  // [128][32]
  __shared__ short Bs[4096];  // [128][32]
  const int t = threadIdx.x;
  const int lane = t & 63;
  const int wave = t >> 6;
  const int l16 = lane & 15;
  const int quad = lane >> 4;
  const int wm = wave >> 1;
  const int wn = wave & 1;

  const short* __restrict__ Ag = cfg.A + (size_t)(ty * 128) * K;
  const short* __restrict__ Wg = cfg.W + (size_t)(tx * 128) * K;
  const int srow = t >> 2;                              // 0..63
  const int ssw = ((t & 3) ^ ((srow >> 1) & 3)) << 3;   // swizzled src chunk
  // (rows srow and srow+64 share the swizzle: 64 == 0 mod 4 after >>1)
  const int rsw = (quad ^ ((l16 >> 1) & 3)) << 3;       // read-side XOR

  const f32x4 z4 = {0.f, 0.f, 0.f, 0.f};
  f32x4 acc[4][4];
#pragma unroll
  for (int i = 0; i < 4; ++i) {
#pragma unroll
    for (int j = 0; j < 4; ++j) acc[i][j] = z4;
  }

  for (int k0 = 0; k0 < K; k0 += 32) {
    gload_lds16(Ag + (size_t)srow * K + k0 + ssw, As + t * 8);
    gload_lds16(Ag + (size_t)(srow + 64) * K + k0 + ssw, As + 2048 + t * 8);
    gload_lds16(Wg + (size_t)srow * K + k0 + ssw, Bs + t * 8);
    gload_lds16(Wg + (size_t)(srow + 64) * K + k0 + ssw, Bs + 2048 + t * 8);
    __syncthreads();
    s16x8 af[4], bfr[4];
#pragma unroll
    for (int i = 0; i < 4; ++i)
      af[i] = *(const s16x8*)(As + (wm * 64 + i * 16 + l16) * 32 + rsw);
#pragma unroll
    for (int i = 0; i < 4; ++i)
      bfr[i] = *(const s16x8*)(Bs + (wn * 64 + i * 16 + l16) * 32 + rsw);
#pragma unroll
    for (int mi = 0; mi < 4; ++mi) {
#pragma unroll
      for (int ni = 0; ni < 4; ++ni)
        acc[mi][ni] = __builtin_amdgcn_mfma_f32_16x16x32_bf16(af[mi], bfr[ni], acc[mi][ni], 0, 0, 0);
    }
    __syncthreads();
  }

  // epilogue: C/D layout col=lane&15, row=quad*4+reg
  const int nbase = tx * 128 + wn * 64;   // 64-aligned -> one head/wave
  const int mbase = ty * 128 + wm * 64;
  const int mode = cfg.mode;
  const int h = nbase >> 6;

  float biasv[4], nwv[4];
#pragma unroll
  for (int ni = 0; ni < 4; ++ni) {
    int col = nbase + ni * 16 + l16;
    biasv[ni] = cfg.bias[col];
    nwv[ni] = (mode == MODE_Q || mode == MODE_K) ? cfg.normw[col & 63] : 0.f;
  }

#pragma unroll
  for (int mi = 0; mi < 4; ++mi) {
    float vv[4][4];
#pragma unroll
    for (int ni = 0; ni < 4; ++ni) {
#pragma unroll
      for (int r = 0; r < 4; ++r) vv[ni][r] = acc[mi][ni][r] + biasv[ni];
    }
    if (mode == MODE_Q || mode == MODE_K) {
      float ss[4];
#pragma unroll
      for (int r = 0; r < 4; ++r)
        ss[r] = vv[0][r] * vv[0][r] + vv[1][r] * vv[1][r] +
                vv[2][r] * vv[2][r] + vv[3][r] * vv[3][r];
#pragma unroll
      for (int r = 0; r < 4; ++r) {
        ss[r] += __shfl_xor(ss[r], 1);
        ss[r] += __shfl_xor(ss[r], 2);
        ss[r] += __shfl_xor(ss[r], 4);
        ss[r] += __shfl_xor(ss[r], 8);
        float rs = rsqrtf(ss[r] * (1.0f / 64.0f) + 1e-6f);
#pragma unroll
        for (int ni = 0; ni < 4; ++ni) vv[ni][r] *= rs * nwv[ni];
      }
    }
    const int row0 = mbase + mi * 16 + quad * 4;  // + r
    if (mode == MODE_Q) {
      short* Qd = (short*)cfg.dst;  // [24][2048][64]
#pragma unroll
      for (int ni = 0; ni < 4; ++ni) {
        int d = ni * 16 + l16;
#pragma unroll
        for (int r = 0; r < 4; ++r)
          Qd[((size_t)h * 2048 + row0 + r) * 64 + d] = f2bf(vv[ni][r]);
      }
    } else if (mode == MODE_K) {
      short* Kd = (short*)cfg.dst;  // [24][2304][64]
#pragma unroll
      for (int ni = 0; ni < 4; ++ni) {
        int d = ni * 16 + l16;
#pragma unroll
        for (int r = 0; r < 4; ++r)
          Kd[((size_t)h * 2304 + cfg.toff + row0 + r) * 64 + d] = f2bf(vv[ni][r]);
      }
    } else if (mode == MODE_V) {
      short* Vd = (short*)cfg.dst;  // V^T: [24][64][2304]
#pragma unroll
      for (int ni = 0; ni < 4; ++ni) {
        int d = ni * 16 + l16;
        short4 o4;
        o4.x = f2bf(vv[ni][0]); o4.y = f2bf(vv[ni][1]);
        o4.z = f2bf(vv[ni][2]); o4.w = f2bf(vv[ni][3]);
        *(short4*)(Vd + ((size_t)h * 64 + d) * 2304 + cfg.toff + row0) = o4;
      }
    } else {  // MODE_OUT: fp32 row-major [2048][1536]
      float* Od = (float*)cfg.dst;
#pragma unroll
      for (int ni = 0; ni < 4; ++ni) {
        int col = nbase + ni * 16 + l16;
#pragma unroll
        for (int r = 0; r < 4; ++r)
          Od[(size_t)(row0 + r) * 1536 + col] = vv[ni][r];
      }
    }
  }
}

// ---------------------------------------------------------------------------
// Flash attention v7: block = (64 q-rows, head). Wave w: qw=w&1 owns 32
// q-rows (two 16-row groups), ks=w>>1 owns a 1152-k stream (36 x 32-t tiles).
// QK^T SWAPPED (mfma(K,Q)) with sigma-permuted K rows so the lane's 8 post-
// exp2 P values (cvt_pk-packed) form the PV 16x16x32 A-fragment in registers.
// l = P @ ones via MFMA (C-layout row=quad*4+rr matches o). mask*LOG2E
// pre-tabulated. Staging offsets hoisted. LDS 32KB, grid 768.
// ---------------------------------------------------------------------------
__global__ __launch_bounds__(256) void flash_kernel(
    const short* __restrict__ Q, const short* __restrict__ Kc,
    const short* __restrict__ VT, const float* __restrict__ mlt,
    short* __restrict__ AO) {
  const int b = blockIdx.x;
  const int h = (b & 7) * 3 + ((b >> 3) % 3);
  const int q0 = ((b >> 3) / 3) * 64;
  const int lane = threadIdx.x & 63;
  const int wave = threadIdx.x >> 6;
  const int qw = wave & 1;   // which 32-row q half
  const int ks = wave >> 1;  // k stream
  const int l16 = lane & 15;
  const int quad = lane >> 4;

  // shorts: Kt (ks*2+buf)*2048 @0 ; Vt @8192. 32 KB total.
  __shared__ __align__(16) short smem[16384];

  const short* Kh = Kc + (size_t)h * 2304 * 64;
  const short* Vh = VT + (size_t)h * 64 * 2304;

  // Q fragments for this wave's two 16-row groups (B-operand in swapped QK^T)
  s16x8 aq0[2], aq1[2];
#pragma unroll
  for (int g = 0; g < 2; ++g) {
    const short* Qrow =
        Q + ((size_t)h * 2048 + q0 + qw * 32 + g * 16 + l16) * 64;
    aq0[g] = *(const s16x8*)(Qrow + quad * 8);
    aq1[g] = *(const s16x8*)(Qrow + quad * 8 + 32);
  }

  s16x8 ones;
#pragma unroll
  for (int i = 0; i < 8; ++i) ones[i] = (short)0x3F80;  // bf16 1.0

  const f32x4 z4 = {0.f, 0.f, 0.f, 0.f};
  f32x4 o[2][4];
#pragma unroll
  for (int g = 0; g < 2; ++g)
#pragma unroll
    for (int mi = 0; mi < 4; ++mi) o[g][mi] = z4;
  f32x4 lacc[2] = {z4, z4};
  const float SC = 0.125f * LOG2E;
  const int kbase = ks * 1152;

  // hoisted per-lane staging source offsets (c=0; c=1 = +256 / +32*2304):
  // K: trow=gi>>3 in [0,16), srow=((trow&12)<<1)|(trow&3), chunk=cp^(trow&7)
  // V: d=gi>>2 in [0,32), chunk=cpv^((d>>1)&3)
  const int gi0 = qw * 64 + lane;
  const int trow0 = gi0 >> 3, cp0 = gi0 & 7;
  const int srow0 = ((trow0 & 12) << 1) | (trow0 & 3);
  const int d0 = gi0 >> 2, cpv0 = gi0 & 3;
  const short* kS = Kh + (size_t)kbase * 64 + srow0 * 64 + ((cp0 ^ (trow0 & 7)) << 3);
  const short* vS = Vh + (size_t)d0 * 2304 + kbase + ((cpv0 ^ ((d0 >> 1) & 3)) << 3);
  const int ldst = qw * 512 + lane * 8;   // wave-uniform base + lane*16B

  auto stage = [&](int it, int buf) {
    short* kt = smem + (ks * 2 + buf) * 2048;
    short* vt = smem + 8192 + (ks * 2 + buf) * 2048;
    const short* ksrc = kS + it * 2048;
    const short* vsrc = vS + it * 32;
    gload_lds16(ksrc,             kt + ldst);
    gload_lds16(ksrc + 256,       kt + 1024 + ldst);
    gload_lds16(vsrc,             vt + ldst);
    gload_lds16(vsrc + 32 * 2304, vt + 1024 + ldst);
  };

  stage(0, 0);
  __syncthreads();

#pragma unroll 2
  for (int it = 0; it < 36; ++it) {
    const int buf = it & 1;
    if (it < 35) stage(it + 1, buf ^ 1);
    const short* kt = smem + (ks * 2 + buf) * 2048;
    const short* vt = smem + 8192 + (ks * 2 + buf) * 2048;
    const int kb = kbase + it * 32;

    // K fragments (A-operand of swapped QK^T): rows = permuted keys
    s16x8 bk[2][2];
#pragma unroll
    for (int ni = 0; ni < 2; ++ni) {
      const int tt = ni * 16 + l16;
      const short* kr = kt + tt * 64;
      bk[ni][0] = *(const s16x8*)(kr + ((quad ^ (tt & 7)) << 3));
      bk[ni][1] = *(const s16x8*)(kr + (((quad + 4) ^ (tt & 7)) << 3));
    }
    // V fragments (B-operand of PV, k=quad*8+j): shared by both q-groups
    s16x8 bv[4];
#pragma unroll
    for (int mi = 0; mi < 4; ++mi) {
      const int d = mi * 16 + l16;
      bv[mi] = *(const s16x8*)(vt + d * 32 + ((quad ^ ((d >> 1) & 3)) << 3));
    }
    // mask*LOG2E for this lane's 8 keys: k = kb + quad*8 + {0..7}
    float4 mv0 = *(const float4*)(mlt + kb + quad * 8);
    float4 mv1 = *(const float4*)(mlt + kb + quad * 8 + 4);
    const float m8[8] = {mv0.x, mv0.y, mv0.z, mv0.w, mv1.x, mv1.y, mv1.z, mv1.w};

#pragma unroll
    for (int g = 0; g < 2; ++g) {
      union { uint32_t w[4]; s16x8 v; } pu;
#pragma unroll
      for (int ni = 0; ni < 2; ++ni) {
        // S^T tile: lane holds q=l16, k(actual) = quad*8 + ni*4 + rr
        f32x4 s = __builtin_amdgcn_mfma_f32_16x16x32_bf16(bk[ni][0], aq0[g], z4, 0, 0, 0);
        s = __builtin_amdgcn_mfma_f32_16x16x32_bf16(bk[ni][1], aq1[g], s, 0, 0, 0);
        float p[4];
#pragma unroll
        for (int rr = 0; rr < 4; ++rr)
          p[rr] = __builtin_amdgcn_exp2f(fmaf(s[rr], SC, m8[ni * 4 + rr]));
        pu.w[ni * 2 + 0] = cvt_pk_bf16(p[0], p[1]);
        pu.w[ni * 2 + 1] = cvt_pk_bf16(p[2], p[3]);
      }
      // pu.v IS the PV A-fragment: element j = P[q=l16][k=quad*8+j]
      lacc[g] = __builtin_amdgcn_mfma_f32_16x16x32_bf16(pu.v, ones, lacc[g], 0, 0, 0);
#pragma unroll
      for (int mi = 0; mi < 4; ++mi)
        o[g][mi] = __builtin_amdgcn_mfma_f32_16x16x32_bf16(pu.v, bv[mi], o[g][mi], 0, 0, 0);
    }
    __syncthreads();   // next tile's staging landed during compute
  }

  // cross-stream combine: ks=1 dumps (o, l) to LDS, ks=0 sums and writes.
  // Both o and lacc have C-layout row=quad*4+rr, so normalize is direct.
  f32x4* R = (f32x4*)smem;               // [128][10] f32x4 = 20 KB
  if (ks == 1) {
    f32x4* Rw = R + (qw * 64 + lane) * 10;
#pragma unroll
    for (int g = 0; g < 2; ++g) {
#pragma unroll
      for (int mi = 0; mi < 4; ++mi) Rw[g * 5 + mi] = o[g][mi];
      Rw[g * 5 + 4] = lacc[g];
    }
  }
  __syncthreads();
  if (ks == 0) {
    const f32x4* Rw = R + (qw * 64 + lane) * 10;
#pragma unroll
    for (int g = 0; g < 2; ++g) {
#pragma unroll
      for (int mi = 0; mi < 4; ++mi) o[g][mi] += Rw[g * 5 + mi];
      f32x4 lt = lacc[g] + Rw[g * 5 + 4];
#pragma unroll
      for (int rr = 0; rr < 4; ++rr) {
        float inv = 1.0f / lt[rr];
        int tq = q0 + qw * 32 + g * 16 + quad * 4 + rr;
#pragma unroll
        for (int mi = 0; mi < 4; ++mi)
          AO[(size_t)tq * 1536 + h * 64 + mi * 16 + l16] = f2bf(o[g][mi][rr] * inv);
      }
    }
  }
}

// ---------------------------------------------------------------------------
extern "C" void kernel_launch(void* const* d_in, const int* in_sizes, int n_in,
                              void* d_out, int out_size, void* d_ws, size_t ws_size,
                              hipStream_t stream) {
  (void)in_sizes; (void)n_in; (void)out_size; (void)ws_size;
  const float* hidden = (const float*)d_in[0];
  const float* enc    = (const float*)d_in[1];
  const float* amask  = (const float*)d_in[2];
  const float* wq  = (const float*)d_in[3];  const float* bq  = (const float*)d_in[4];
  const float* wk  = (const float*)d_in[5];  const float* bk  = (const float*)d_in[6];
  const float* wv  = (const float*)d_in[7];  const float* bv  = (const float*)d_in[8];
  const float* nqw = (const float*)d_in[9];  const float* nkw = (const float*)d_in[10];
  // d_in[11],[12],[17]: add_q_proj + norm_added_q -> dead (context q unused)
  const float* wak = (const float*)d_in[13]; const float* bak = (const float*)d_in[14];
  const float* wav = (const float*)d_in[15]; const float* bav = (const float*)d_in[16];
  const float* nakw = (const float*)d_in[18];
  const float* wo  = (const float*)d_in[19]; const float* bo  = (const float*)d_in[20];
  // d_in[21],[22]: to_add_out -> dead
  float* out = (float*)d_out;

  char* p = (char*)d_ws;
  auto carve = [&](size_t bytes) { char* r = p; p += (bytes + 255) & ~(size_t)255; return r; };
  short* Xb   = (short*)carve((size_t)2048 * 1536 * 2);
  short* Eb   = (short*)carve((size_t)256 * 1536 * 2);
  short* Wqb  = (short*)carve((size_t)1536 * 1536 * 2);
  short* Wkb  = (short*)carve((size_t)1536 * 1536 * 2);
  short* Wvb  = (short*)carve((size_t)1536 * 1536 * 2);
  short* Wakb = (short*)carve((size_t)1536 * 1536 * 2);
  short* Wavb = (short*)carve((size_t)1536 * 1536 * 2);
  short* Wob  = (short*)carve((size_t)1536 * 1536 * 2);
  short* Qb   = (short*)carve((size_t)24 * 2048 * 64 * 2);
  short* Kb   = (short*)carve((size_t)24 * 2304 * 64 * 2);
  short* VTb  = (short*)carve((size_t)24 * 64 * 2304 * 2);
  short* AOb  = (short*)carve((size_t)2048 * 1536 * 2);
  float* MLb  = (float*)carve((size_t)2304 * 4);

  CvtArgs ca;
  ca.s[0] = {hidden, Xb, 2048 * 1536 / 4};
  ca.s[1] = {enc,    Eb, 256 * 1536 / 4};
  ca.s[2] = {wq,  Wqb,  1536 * 1536 / 4};
  ca.s[3] = {wk,  Wkb,  1536 * 1536 / 4};
  ca.s[4] = {wv,  Wvb,  1536 * 1536 / 4};
  ca.s[5] = {wak, Wakb, 1536 * 1536 / 4};
  ca.s[6] = {wav, Wavb, 1536 * 1536 / 4};
  ca.s[7] = {wo,  Wob,  1536 * 1536 / 4};
  ca.msrc = amask; ca.mdst = MLb; ca.mn4 = 2304 / 4;
  cvt_bf16_kernel<<<dim3(1024), dim3(256), 0, stream>>>(ca);

  GemmArgs g1;  // all five projections, 1D worklist of 624 tiles
  g1.c[0] = {Xb, Wqb,  bq,  nqw,     (void*)Qb,  0,    MODE_Q, 0};
  g1.c[1] = {Xb, Wkb,  bk,  nkw,     (void*)Kb,  0,    MODE_K, 0};
  g1.c[2] = {Xb, Wvb,  bv,  nullptr, (void*)VTb, 0,    MODE_V, 0};
  g1.c[3] = {Eb, Wakb, bak, nakw,    (void*)Kb,  2048, MODE_K, 0};
  g1.c[4] = {Eb, Wavb, bav, nullptr, (void*)VTb, 2048, MODE_V, 0};
  proj_gemm_kernel<<<dim3(624), dim3(256), 0, stream>>>(g1, 78);

  flash_kernel<<<dim3(768), dim3(256), 0, stream>>>(Qb, Kb, VTb, MLb, AOb);

  GemmArgs g3;  // out projection -> fp32 d_out (192 tiles, w<192 -> z=0)
  g3.c[0] = {AOb, Wob, bo, nullptr, (void*)out, 0, MODE_OUT, 0};
  proj_gemm_kernel<<<dim3(192), dim3(256), 0, stream>>>(g3, 24);
}